// Round 5
// baseline (668.284 us; speedup 1.0000x reference)
//
#include <hip/hip_runtime.h>
#include <hip/hip_bf16.h>

#define DI __device__ __forceinline__

typedef short bf16x8 __attribute__((ext_vector_type(8)));
typedef float f32x4 __attribute__((ext_vector_type(4)));

typedef __attribute__((address_space(3))) unsigned lds_u32;
typedef __attribute__((address_space(1))) const unsigned g_u32;

DI void gload16(const void* g, void* lds) {
  __builtin_amdgcn_global_load_lds((g_u32*)g, (lds_u32*)lds, 16, 0, 0);
}

DI unsigned short bf16bits(float f) {
  __hip_bfloat16 h = __float2bfloat16(f);
  return *(unsigned short*)&h;
}

// ---------------------------------------------------------------------------
// Weight transpose: W[K][N] fp32 -> Wt[N][K] bf16 (tiled via LDS)
// ---------------------------------------------------------------------------
__global__ __launch_bounds__(256)
void wtrans_kernel(const float* __restrict__ w, __hip_bfloat16* __restrict__ wt,
                   int K, int N) {
  __shared__ float tile[32][33];
  const int nb = blockIdx.x * 32, kb = blockIdx.y * 32;
  const int tx = threadIdx.x & 31, ty = threadIdx.x >> 5;  // 32 x 8
#pragma unroll
  for (int i = 0; i < 4; ++i)
    tile[ty + i * 8][tx] = w[(size_t)(kb + ty + i * 8) * N + nb + tx];
  __syncthreads();
#pragma unroll
  for (int i = 0; i < 4; ++i)
    wt[(size_t)(nb + ty + i * 8) * K + kb + tx] = __float2bfloat16(tile[tx][ty + i * 8]);
}

// ---------------------------------------------------------------------------
// RoPE cos/sin tables: [576][64] each
// ---------------------------------------------------------------------------
__global__ void tables_kernel(float* __restrict__ cost, float* __restrict__ sint) {
  const int s = blockIdx.x;    // 0..575
  const int d = threadIdx.x;   // 0..63
  const int j = d >> 1;
  const float pos = (j < 16) ? (float)(s % 24) * (1.0f / 3.0f)
                             : (float)(s / 24) * (1.0f / 3.0f);
  const int fi = j & 15;
  const float freq = powf(10000.0f, -(float)fi * (1.0f / 16.0f));
  const float a = pos * freq;
  cost[s * 64 + d] = cosf(a);
  sint[s * 64 + d] = sinf(a);
}

// ---------------------------------------------------------------------------
// LayerNorm: fp32 in -> bf16 out, one block per token (1024 ch, 256 thr x 4)
// ---------------------------------------------------------------------------
__global__ __launch_bounds__(256)
void ln_kernel(const float* __restrict__ in, const float* __restrict__ g,
               const float* __restrict__ b, __hip_bfloat16* __restrict__ out) {
  const int t = blockIdx.x, tid = threadIdx.x;
  const float4 x = *(const float4*)(in + (size_t)t * 1024 + tid * 4);
  float s = x.x + x.y + x.z + x.w;
  float sq = x.x * x.x + x.y * x.y + x.z * x.z + x.w * x.w;
#pragma unroll
  for (int off = 32; off >= 1; off >>= 1) {
    s += __shfl_down(s, off);
    sq += __shfl_down(sq, off);
  }
  __shared__ float red[8];
  const int wave = tid >> 6, lane = tid & 63;
  if (lane == 0) { red[wave] = s; red[4 + wave] = sq; }
  __syncthreads();
  s = red[0] + red[1] + red[2] + red[3];
  sq = red[4] + red[5] + red[6] + red[7];
  const float mean = s * (1.0f / 1024.0f);
  const float var = sq * (1.0f / 1024.0f) - mean * mean;
  const float rstd = rsqrtf(var + 1e-6f);
  const int c = tid * 4;
  const float4 gg = *(const float4*)(g + c);
  const float4 bb = *(const float4*)(b + c);
  ushort4 o;
  o.x = bf16bits((x.x - mean) * rstd * gg.x + bb.x);
  o.y = bf16bits((x.y - mean) * rstd * gg.y + bb.y);
  o.z = bf16bits((x.z - mean) * rstd * gg.z + bb.z);
  o.w = bf16bits((x.w - mean) * rstd * gg.w + bb.w);
  *(ushort4*)((unsigned short*)out + (size_t)t * 1024 + c) = o;
}

// ---------------------------------------------------------------------------
// GEMM: C[M,N] = A[M,K] @ Bt[N,K]^T, bf16 inputs, fp32 accum.
// 128x128 tile, BK=64, 256 threads (4 waves, 2x2 of 64x64), 16x16x32 MFMA.
// Single-buffer r4 core (conflict-free granule-XOR; fastest measured).
// NEW: LDS-repack epilogue — each wave stages its 64x64 C tile into its
// private 8KB slice of the dead As/Bs LDS (XOR-swizzled), then reads rows
// back 16B/lane and issues coalesced 1KB wave-stores. Kills the 2x HBM
// write amplification of scalar bf16/f32 stores and 8x's store-instr count.
// MODE 0: out bf16 = acc + bias
// MODE 1: out bf16 = gelu(acc + bias)
// MODE 2: out f32 += acc + bias     (vectorized float4 RMW)
// MODE 3: window-unpartition row perm; out f32[t] = resid[t] + acc + bias
// ---------------------------------------------------------------------------
template<int MODE>
__global__ __launch_bounds__(256)
void gemm_bt_kernel(const __hip_bfloat16* __restrict__ A,
                    const __hip_bfloat16* __restrict__ Bt,
                    const float* __restrict__ bias,
                    void* __restrict__ out,
                    const float* __restrict__ resid,
                    int M, int N, int K) {
  __shared__ __hip_bfloat16 smem[2 * 128 * 64];
  __hip_bfloat16* As = smem;
  __hip_bfloat16* Bs = smem + 128 * 64;
  const int tid = threadIdx.x;
  const int wave = tid >> 6, lane = tid & 63;
  const int lr = lane & 15, lg = lane >> 4;
  // bijective XCD swizzle (m204)
  const unsigned nwg = gridDim.x * gridDim.y;
  const unsigned bid0 = blockIdx.y * gridDim.x + blockIdx.x;
  const unsigned xcd = bid0 & 7u, idx = bid0 >> 3;
  const unsigned q8 = nwg >> 3, r8 = nwg & 7u;
  const unsigned L = (xcd < r8 ? xcd * (q8 + 1u)
                               : r8 * (q8 + 1u) + (xcd - r8) * q8) + idx;
  const int bm = (int)(L / gridDim.x) * 128;
  const int bn = (int)(L % gridDim.x) * 128;
  const int wr = (wave >> 1) * 64, wc = (wave & 1) * 64;
  const int srow = lane >> 3;                       // 0..7 (LDS row mod 8)
  const int scol = ((lane & 7) ^ srow) * 8;         // pre-swizzled source col
  const int rsw = lr & 7;                           // read-side XOR key

  f32x4 acc[4][4] = {};

  for (int k0 = 0; k0 < K; k0 += 64) {
#pragma unroll
    for (int c = 0; c < 4; ++c) {
      const int ch = wave * 4 + c;
      gload16(A + (size_t)(bm + ch * 8 + srow) * K + k0 + scol, &As[ch * 512]);
      gload16(Bt + (size_t)(bn + ch * 8 + srow) * K + k0 + scol, &Bs[ch * 512]);
    }
    __syncthreads();
#pragma unroll
    for (int kk = 0; kk < 64; kk += 32) {
      const int kg = kk >> 3;  // granule base: 0 or 4
      bf16x8 af[4], bfr[4];
#pragma unroll
      for (int i = 0; i < 4; ++i)
        af[i] = *(const bf16x8*)&As[(wr + i * 16 + lr) * 64 + (((kg + lg) ^ rsw) * 8)];
#pragma unroll
      for (int i = 0; i < 4; ++i)
        bfr[i] = *(const bf16x8*)&Bs[(wc + i * 16 + lr) * 64 + (((kg + lg) ^ rsw) * 8)];
#pragma unroll
      for (int mi = 0; mi < 4; ++mi)
#pragma unroll
        for (int ni = 0; ni < 4; ++ni)
          acc[mi][ni] = __builtin_amdgcn_mfma_f32_16x16x32_bf16(af[mi], bfr[ni],
                                                                acc[mi][ni], 0, 0, 0);
    }
    __syncthreads();
  }

  // ---- LDS-repack epilogue (per-wave private 8KB slice; no barrier needed:
  // last __syncthreads of the K-loop already separates all waves) ----
  __hip_bfloat16* stg = smem + wave * 4096;
  if (MODE == 0 || MODE == 1) {
#pragma unroll
    for (int ni = 0; ni < 4; ++ni) {
      const int gn = bn + wc + ni * 16 + lr;
      const float bv = bias ? bias[gn] : 0.0f;
#pragma unroll
      for (int mi = 0; mi < 4; ++mi) {
#pragma unroll
        for (int j = 0; j < 4; ++j) {
          float v = acc[mi][ni][j] + bv;
          if (MODE == 1) v = 0.5f * v * (1.0f + erff(v * 0.70710678f));
          const int row = mi * 16 + lg * 4 + j;
          const int col = ni * 16 + lr;
          stg[row * 64 + (((col >> 3) ^ (row & 7)) * 8) + (col & 7)] =
              __float2bfloat16(v);
        }
      }
    }
    asm volatile("s_waitcnt lgkmcnt(0)" ::: "memory");
#pragma unroll
    for (int pass = 0; pass < 8; ++pass) {
      const int row = pass * 8 + (lane >> 3);
      const int g = (lane & 7) ^ (row & 7);
      const bf16x8 v = *(const bf16x8*)&stg[row * 64 + g * 8];
      *(bf16x8*)((__hip_bfloat16*)out + (size_t)(bm + wr + row) * N
                 + bn + wc + (lane & 7) * 8) = v;
    }
  } else {
    float* stf = (float*)stg;  // 2048 f32 = 32 rows x 64 cols (half tile)
#pragma unroll
    for (int half = 0; half < 2; ++half) {
#pragma unroll
      for (int ni = 0; ni < 4; ++ni) {
        const int gn = bn + wc + ni * 16 + lr;
        const float bv = bias ? bias[gn] : 0.0f;
#pragma unroll
        for (int mi2 = 0; mi2 < 2; ++mi2) {
          const int mi = half * 2 + mi2;
#pragma unroll
          for (int j = 0; j < 4; ++j) {
            const float v = acc[mi][ni][j] + bv;
            const int row = mi2 * 16 + lg * 4 + j;   // 0..31 local
            const int col = ni * 16 + lr;
            stf[row * 64 + (((col >> 2) ^ (row & 7)) * 4) + (col & 3)] = v;
          }
        }
      }
      asm volatile("s_waitcnt lgkmcnt(0)" ::: "memory");
#pragma unroll
      for (int pass = 0; pass < 8; ++pass) {
        const int rloc = pass * 4 + (lane >> 4);
        const int g = (lane & 15) ^ (rloc & 7);
        const f32x4 v = *(const f32x4*)&stf[rloc * 64 + g * 4];
        const int gm = bm + wr + half * 32 + rloc;
        const int gn0 = bn + wc + (lane & 15) * 4;
        if (MODE == 2) {
          float4 o = *(float4*)((float*)out + (size_t)gm * N + gn0);
          o.x += v[0]; o.y += v[1]; o.z += v[2]; o.w += v[3];
          *(float4*)((float*)out + (size_t)gm * N + gn0) = o;
        } else {
          const int win = gm / 576, s = gm % 576;
          const int bb2 = win / 9, wi = (win % 9) / 3, wj = win % 3;
          const int t2 = (bb2 * 72 + wi * 24 + (s / 24)) * 72 + wj * 24 + (s % 24);
          const float4 rr = *(const float4*)(resid + (size_t)t2 * 1024 + gn0);
          float4 o;
          o.x = rr.x + v[0]; o.y = rr.y + v[1];
          o.z = rr.z + v[2]; o.w = rr.w + v[3];
          *(float4*)((float*)out + (size_t)t2 * 1024 + gn0) = o;
        }
      }
      // next half's LDS writes are ordered after these reads by the in-order
      // per-wave LDS pipeline (same idiom as attn P staging).
      asm volatile("s_waitcnt lgkmcnt(0)" ::: "memory");
    }
  }
}

// ---------------------------------------------------------------------------
// RoPE + bias + window scatter for Q (pre-scaled by 0.125) and K.
// ---------------------------------------------------------------------------
__global__ __launch_bounds__(256)
void rope_kernel(const __hip_bfloat16* __restrict__ qkvraw,
                 const float* __restrict__ bq, const float* __restrict__ bk,
                 const float* __restrict__ cost, const float* __restrict__ sint,
                 __hip_bfloat16* __restrict__ qw, __hip_bfloat16* __restrict__ kw) {
  const int s = blockIdx.x;    // 0..575
  const int win = blockIdx.y;  // 0..17
  const int b = win / 9, wi = (win % 9) / 3, wj = win % 3;
  const int t = (b * 72 + wi * 24 + (s / 24)) * 72 + wj * 24 + (s % 24);
  const int tid = threadIdx.x;
  const int col = tid * 4;           // 0..1020, aligned pairs
  const int head = col >> 6, d = col & 63;
  const float c0 = cost[s * 64 + d + 0], c1 = cost[s * 64 + d + 1];
  const float c2 = cost[s * 64 + d + 2], c3 = cost[s * 64 + d + 3];
  const float s0 = sint[s * 64 + d + 0], s1 = sint[s * 64 + d + 1];
  const float s2 = sint[s * 64 + d + 2], s3 = sint[s * 64 + d + 3];
  const size_t rbase = (size_t)t * 3072;
  const size_t obase = (((size_t)(win * 16 + head)) * 576 + s) * 64 + d;
  {  // Q (fold softmax scale 1/8)
    const float q0 = __bfloat162float(qkvraw[rbase + col + 0]) + bq[col + 0];
    const float q1 = __bfloat162float(qkvraw[rbase + col + 1]) + bq[col + 1];
    const float q2 = __bfloat162float(qkvraw[rbase + col + 2]) + bq[col + 2];
    const float q3 = __bfloat162float(qkvraw[rbase + col + 3]) + bq[col + 3];
    ushort4 o;
    o.x = bf16bits(0.125f * (q0 * c0 - q1 * s0));
    o.y = bf16bits(0.125f * (q1 * c1 + q0 * s1));
    o.z = bf16bits(0.125f * (q2 * c2 - q3 * s2));
    o.w = bf16bits(0.125f * (q3 * c3 + q2 * s3));
    *(ushort4*)((unsigned short*)qw + obase) = o;
  }
  {  // K
    const float k0 = __bfloat162float(qkvraw[rbase + 1024 + col + 0]) + bk[col + 0];
    const float k1 = __bfloat162float(qkvraw[rbase + 1024 + col + 1]) + bk[col + 1];
    const float k2 = __bfloat162float(qkvraw[rbase + 1024 + col + 2]) + bk[col + 2];
    const float k3 = __bfloat162float(qkvraw[rbase + 1024 + col + 3]) + bk[col + 3];
    ushort4 o;
    o.x = bf16bits(k0 * c0 - k1 * s0);
    o.y = bf16bits(k1 * c1 + k0 * s1);
    o.z = bf16bits(k2 * c2 - k3 * s2);
    o.w = bf16bits(k3 * c3 + k2 * s3);
    *(ushort4*)((unsigned short*)kw + obase) = o;
  }
}

// ---------------------------------------------------------------------------
// V: bias + window gather + transpose: vt[win][head][d][s] bf16 (for PV MFMA)
// ---------------------------------------------------------------------------
__global__ __launch_bounds__(256)
void vtrans_kernel(const __hip_bfloat16* __restrict__ qkvraw,
                   const float* __restrict__ bv,
                   __hip_bfloat16* __restrict__ vt) {
  const int head = blockIdx.x, win = blockIdx.y;
  const int b = win / 9, wi = (win % 9) / 3, wj = win % 3;
  __shared__ __hip_bfloat16 tile[64][72];
  const int tid = threadIdx.x;
  for (int s0 = 0; s0 < 576; s0 += 64) {
#pragma unroll
    for (int rep = 0; rep < 16; ++rep) {
      const int e = rep * 256 + tid;  // 0..4095
      const int si = e >> 6, d = e & 63;
      const int s = s0 + si;
      const int t = (b * 72 + wi * 24 + (s / 24)) * 72 + wj * 24 + (s % 24);
      const float v = __bfloat162float(qkvraw[(size_t)t * 3072 + 2048 + head * 64 + d])
                    + bv[head * 64 + d];
      tile[d][si] = __float2bfloat16(v);
    }
    __syncthreads();
#pragma unroll
    for (int rep = 0; rep < 16; ++rep) {
      const int e = rep * 256 + tid;
      const int d = e >> 6, si = e & 63;
      vt[((size_t)(win * 16 + head) * 64 + d) * 576 + s0 + si] = tile[d][si];
    }
    __syncthreads();
  }
}

// ---------------------------------------------------------------------------
// Flash attention per (qtile, head, win). 256 thr = 4 waves, 16 q-rows/wave.
// K/V LDS uses the granule-XOR swizzle (16-way -> 2-way). O output repacked
// through the per-wave Plds slice for coalesced 16B stores.
// ---------------------------------------------------------------------------
__global__ __launch_bounds__(256)
void attn_kernel(const __hip_bfloat16* __restrict__ qw,
                 const __hip_bfloat16* __restrict__ kw,
                 const __hip_bfloat16* __restrict__ vt,
                 __hip_bfloat16* __restrict__ ow) {
  __shared__ __hip_bfloat16 Klds[2][64 * 64];
  __shared__ __hip_bfloat16 Vlds[2][64 * 64];
  __shared__ __hip_bfloat16 Plds[4 * 16 * 64];
  const unsigned nwg = gridDim.x * gridDim.y * gridDim.z;
  const unsigned bid0 = (blockIdx.z * gridDim.y + blockIdx.y) * gridDim.x + blockIdx.x;
  const unsigned Lw = (bid0 & 7u) * (nwg >> 3) + (bid0 >> 3);
  const int qt = (int)(Lw % 9u);          // 0..8
  const unsigned r = Lw / 9u;
  const int head = (int)(r & 15u);        // 0..15
  const int win = (int)(r >> 4);          // 0..17
  const int bh = win * 16 + head;
  const int tid = threadIdx.x, wave = tid >> 6, lane = tid & 63;
  const int lr = lane & 15, lg = lane >> 4;
  const int rsw = lr & 7;

  const int qrow = qt * 64 + wave * 16 + lr;
  const __hip_bfloat16* qbase = qw + ((size_t)bh * 576 + qrow) * 64;
  const bf16x8 q0 = *(const bf16x8*)(qbase + lg * 8);
  const bf16x8 q1 = *(const bf16x8*)(qbase + 32 + lg * 8);

  f32x4 oacc[4] = {};
  float mrow[4] = {-1e30f, -1e30f, -1e30f, -1e30f};
  float lrow[4] = {};

  const int srow = lane >> 3;
  const int sw = ((lane & 7) ^ srow) * 8;  // pre-swizzled source col

  auto stagekv = [&](int buf, int kv) {
#pragma unroll
    for (int c = 0; c < 2; ++c) {
      const int ch = wave * 2 + c;
      gload16(kw + ((size_t)bh * 576 + kv * 64 + ch * 8 + srow) * 64 + sw,
              &Klds[buf][ch * 512]);
      gload16(vt + ((size_t)bh * 64 + ch * 8 + srow) * 576 + kv * 64 + sw,
              &Vlds[buf][ch * 512]);
    }
  };

  stagekv(0, 0);
  __syncthreads();

  for (int kv = 0; kv < 9; ++kv) {
    const int cur = kv & 1;
    if (kv + 1 < 9) stagekv(cur ^ 1, kv + 1);
    __builtin_amdgcn_sched_barrier(0);

    f32x4 sfr[4];
#pragma unroll
    for (int c = 0; c < 4; ++c) {
      const bf16x8 b0 = *(const bf16x8*)&Klds[cur][(c * 16 + lr) * 64 + ((lg ^ rsw) * 8)];
      const bf16x8 b1 = *(const bf16x8*)&Klds[cur][(c * 16 + lr) * 64 + (((4 + lg) ^ rsw) * 8)];
      f32x4 z = {};
      z = __builtin_amdgcn_mfma_f32_16x16x32_bf16(q0, b0, z, 0, 0, 0);
      z = __builtin_amdgcn_mfma_f32_16x16x32_bf16(q1, b1, z, 0, 0, 0);
      sfr[c] = z;
    }

    float p[4][4], rscale[4];
#pragma unroll
    for (int j = 0; j < 4; ++j) {
      float mj = fmaxf(fmaxf(sfr[0][j], sfr[1][j]), fmaxf(sfr[2][j], sfr[3][j]));
#pragma unroll
      for (int off = 1; off < 16; off <<= 1) mj = fmaxf(mj, __shfl_xor(mj, off));
      const float mn = fmaxf(mrow[j], mj);
      rscale[j] = __expf(mrow[j] - mn);
      mrow[j] = mn;
      float rs = 0.0f;
#pragma unroll
      for (int c = 0; c < 4; ++c) {
        const float pp = __expf(sfr[c][j] - mn);
        p[c][j] = pp;
        rs += pp;
      }
#pragma unroll
      for (int off = 1; off < 16; off <<= 1) rs += __shfl_xor(rs, off);
      lrow[j] = lrow[j] * rscale[j] + rs;
    }
#pragma unroll
    for (int d = 0; d < 4; ++d)
#pragma unroll
      for (int j = 0; j < 4; ++j) oacc[d][j] *= rscale[j];

#pragma unroll
    for (int c = 0; c < 4; ++c)
#pragma unroll
      for (int j = 0; j < 4; ++j)
        Plds[wave * 1024 + (lg * 4 + j) * 64 + c * 16 + lr] = __float2bfloat16(p[c][j]);

    const bf16x8 pa0 = *(const bf16x8*)&Plds[wave * 1024 + lr * 64 + lg * 8];
    const bf16x8 pa1 = *(const bf16x8*)&Plds[wave * 1024 + lr * 64 + 32 + lg * 8];
#pragma unroll
    for (int d = 0; d < 4; ++d) {
      const bf16x8 v0 = *(const bf16x8*)&Vlds[cur][(d * 16 + lr) * 64 + ((lg ^ rsw) * 8)];
      const bf16x8 v1 = *(const bf16x8*)&Vlds[cur][(d * 16 + lr) * 64 + (((4 + lg) ^ rsw) * 8)];
      oacc[d] = __builtin_amdgcn_mfma_f32_16x16x32_bf16(pa0, v0, oacc[d], 0, 0, 0);
      oacc[d] = __builtin_amdgcn_mfma_f32_16x16x32_bf16(pa1, v1, oacc[d], 0, 0, 0);
    }
    __syncthreads();
  }

  // ---- O epilogue: repack through per-wave Plds slice, 16B coalesced ----
  {
    __hip_bfloat16* stg = &Plds[wave * 1024];  // 16 rows x 64 cols
#pragma unroll
    for (int j = 0; j < 4; ++j) {
      const float inv = 1.0f / lrow[j];
      const int row = lg * 4 + j;
#pragma unroll
      for (int d = 0; d < 4; ++d) {
        const int col = d * 16 + lr;
        stg[row * 64 + (((col >> 3) ^ (row & 7)) * 8) + (col & 7)] =
            __float2bfloat16(oacc[d][j] * inv);
      }
    }
    asm volatile("s_waitcnt lgkmcnt(0)" ::: "memory");
#pragma unroll
    for (int pass = 0; pass < 2; ++pass) {
      const int row = pass * 8 + (lane >> 3);
      const int g = (lane & 7) ^ (row & 7);
      const bf16x8 v = *(const bf16x8*)&stg[row * 64 + g * 8];
      const int srow2 = qt * 64 + wave * 16 + row;
      *(bf16x8*)(ow + ((size_t)win * 576 + srow2) * 1024 + head * 64
                 + (lane & 7) * 8) = v;
    }
  }
}

// ---------------------------------------------------------------------------
extern "C" void kernel_launch(void* const* d_in, const int* in_sizes, int n_in,
                              void* d_out, int out_size, void* d_ws, size_t ws_size,
                              hipStream_t stream) {
  const float* hidden = (const float*)d_in[0];
  const float* ln1_g = (const float*)d_in[1];
  const float* ln1_b = (const float*)d_in[2];
  const float* wq = (const float*)d_in[3];
  const float* bq = (const float*)d_in[4];
  const float* wk = (const float*)d_in[5];
  const float* bk = (const float*)d_in[6];
  const float* wv = (const float*)d_in[7];
  const float* bv = (const float*)d_in[8];
  const float* wo = (const float*)d_in[9];
  const float* bo = (const float*)d_in[10];
  const float* ln2_g = (const float*)d_in[11];
  const float* ln2_b = (const float*)d_in[12];
  const float* w1 = (const float*)d_in[13];
  const float* b1 = (const float*)d_in[14];
  const float* w2 = (const float*)d_in[15];
  const float* b2 = (const float*)d_in[16];
  float* out = (float*)d_out;

  char* p = (char*)d_ws;
  auto alloc = [&](size_t bytes) {
    char* r = p;
    p += (bytes + 255) & ~(size_t)255;
    return r;
  };
  __hip_bfloat16* wt_qkv = (__hip_bfloat16*)alloc(3072ull * 1024 * 2);
  __hip_bfloat16* wt_wo  = (__hip_bfloat16*)alloc(1024ull * 1024 * 2);
  __hip_bfloat16* wt_w1  = (__hip_bfloat16*)alloc(4096ull * 1024 * 2);
  __hip_bfloat16* wt_w2  = (__hip_bfloat16*)alloc(1024ull * 4096 * 2);
  float* cost = (float*)alloc(576ull * 64 * 4);
  float* sint = (float*)alloc(576ull * 64 * 4);
  __hip_bfloat16* xbuf = (__hip_bfloat16*)alloc(10368ull * 1024 * 2);  // xln / o_w / xln2
  char* big = alloc(10368ull * 4096 * 2);                              // qkvraw+qw | h1
  __hip_bfloat16* qkvraw = (__hip_bfloat16*)big;
  __hip_bfloat16* qw = (__hip_bfloat16*)(big + 10368ull * 3072 * 2);
  __hip_bfloat16* h1 = (__hip_bfloat16*)big;
  __hip_bfloat16* kw = (__hip_bfloat16*)alloc(18ull * 16 * 576 * 64 * 2);
  __hip_bfloat16* vt = (__hip_bfloat16*)alloc(18ull * 16 * 64 * 576 * 2);

  // weights -> bf16 transposed
  wtrans_kernel<<<dim3(32, 32), 256, 0, stream>>>(wq, wt_qkv, 1024, 1024);
  wtrans_kernel<<<dim3(32, 32), 256, 0, stream>>>(wk, wt_qkv + 1024ull * 1024, 1024, 1024);
  wtrans_kernel<<<dim3(32, 32), 256, 0, stream>>>(wv, wt_qkv + 2048ull * 1024, 1024, 1024);
  wtrans_kernel<<<dim3(32, 32), 256, 0, stream>>>(wo, wt_wo, 1024, 1024);
  wtrans_kernel<<<dim3(128, 32), 256, 0, stream>>>(w1, wt_w1, 1024, 4096);
  wtrans_kernel<<<dim3(32, 128), 256, 0, stream>>>(w2, wt_w2, 4096, 1024);
  tables_kernel<<<576, 64, 0, stream>>>(cost, sint);

  // LN1 -> xln (bf16)
  ln_kernel<<<10368, 256, 0, stream>>>(hidden, ln1_g, ln1_b, xbuf);
  // QKV fused GEMM: [10368,1024] x [3072,1024]^T -> qkvraw bf16
  gemm_bt_kernel<0><<<dim3(24, 81), 256, 0, stream>>>(
      xbuf, wt_qkv, nullptr, qkvraw, nullptr, 10368, 3072, 1024);
  // RoPE + window scatter (q scaled by 0.125); V bias + transpose
  rope_kernel<<<dim3(576, 18), 256, 0, stream>>>(qkvraw, bq, bk, cost, sint, qw, kw);
  vtrans_kernel<<<dim3(16, 18), 256, 0, stream>>>(qkvraw, bv, vt);
  // attention -> o_w (windowed rows, [tw][1024]) into xbuf
  attn_kernel<<<dim3(9, 16, 18), 256, 0, stream>>>(qw, kw, vt, xbuf);
  // Wo GEMM + bias + residual + window-unpartition -> d_out (fp32 x)
  gemm_bt_kernel<3><<<dim3(8, 81), 256, 0, stream>>>(
      xbuf, wt_wo, bo, out, hidden, 10368, 1024, 1024);
  // LN2 -> xln2 (bf16)
  ln_kernel<<<10368, 256, 0, stream>>>(out, ln2_g, ln2_b, xbuf);
  // MLP up + GELU -> h1 bf16
  gemm_bt_kernel<1><<<dim3(32, 81), 256, 0, stream>>>(
      xbuf, wt_w1, b1, h1, nullptr, 10368, 4096, 1024);
  // MLP down, += into d_out
  gemm_bt_kernel<2><<<dim3(8, 81), 256, 0, stream>>>(
      h1, wt_w2, b2, out, nullptr, 10368, 1024, 4096);
}

// Round 6
// 647.181 us; speedup vs baseline: 1.0326x; 1.0326x over previous
//
#include <hip/hip_runtime.h>
#include <hip/hip_bf16.h>

#define DI __device__ __forceinline__

typedef short bf16x8 __attribute__((ext_vector_type(8)));
typedef float f32x4 __attribute__((ext_vector_type(4)));

typedef __attribute__((address_space(3))) unsigned lds_u32;
typedef __attribute__((address_space(1))) const unsigned g_u32;

DI void gload16(const void* g, void* lds) {
  __builtin_amdgcn_global_load_lds((g_u32*)g, (lds_u32*)lds, 16, 0, 0);
}

DI unsigned short bf16bits(float f) {
  __hip_bfloat16 h = __float2bfloat16(f);
  return *(unsigned short*)&h;
}

// ---------------------------------------------------------------------------
// Weight transpose: W[K][N] fp32 -> Wt[N][K] bf16 (tiled via LDS)
// ---------------------------------------------------------------------------
__global__ __launch_bounds__(256)
void wtrans_kernel(const float* __restrict__ w, __hip_bfloat16* __restrict__ wt,
                   int K, int N) {
  __shared__ float tile[32][33];
  const int nb = blockIdx.x * 32, kb = blockIdx.y * 32;
  const int tx = threadIdx.x & 31, ty = threadIdx.x >> 5;  // 32 x 8
#pragma unroll
  for (int i = 0; i < 4; ++i)
    tile[ty + i * 8][tx] = w[(size_t)(kb + ty + i * 8) * N + nb + tx];
  __syncthreads();
#pragma unroll
  for (int i = 0; i < 4; ++i)
    wt[(size_t)(nb + ty + i * 8) * K + kb + tx] = __float2bfloat16(tile[tx][ty + i * 8]);
}

// ---------------------------------------------------------------------------
// RoPE cos/sin tables: [576][64] each
// ---------------------------------------------------------------------------
__global__ void tables_kernel(float* __restrict__ cost, float* __restrict__ sint) {
  const int s = blockIdx.x;    // 0..575
  const int d = threadIdx.x;   // 0..63
  const int j = d >> 1;
  const float pos = (j < 16) ? (float)(s % 24) * (1.0f / 3.0f)
                             : (float)(s / 24) * (1.0f / 3.0f);
  const int fi = j & 15;
  const float freq = powf(10000.0f, -(float)fi * (1.0f / 16.0f));
  const float a = pos * freq;
  cost[s * 64 + d] = cosf(a);
  sint[s * 64 + d] = sinf(a);
}

// ---------------------------------------------------------------------------
// LayerNorm: fp32 in -> bf16 out, one block per token (1024 ch, 256 thr x 4)
// ---------------------------------------------------------------------------
__global__ __launch_bounds__(256)
void ln_kernel(const float* __restrict__ in, const float* __restrict__ g,
               const float* __restrict__ b, __hip_bfloat16* __restrict__ out) {
  const int t = blockIdx.x, tid = threadIdx.x;
  const float4 x = *(const float4*)(in + (size_t)t * 1024 + tid * 4);
  float s = x.x + x.y + x.z + x.w;
  float sq = x.x * x.x + x.y * x.y + x.z * x.z + x.w * x.w;
#pragma unroll
  for (int off = 32; off >= 1; off >>= 1) {
    s += __shfl_down(s, off);
    sq += __shfl_down(sq, off);
  }
  __shared__ float red[8];
  const int wave = tid >> 6, lane = tid & 63;
  if (lane == 0) { red[wave] = s; red[4 + wave] = sq; }
  __syncthreads();
  s = red[0] + red[1] + red[2] + red[3];
  sq = red[4] + red[5] + red[6] + red[7];
  const float mean = s * (1.0f / 1024.0f);
  const float var = sq * (1.0f / 1024.0f) - mean * mean;
  const float rstd = rsqrtf(var + 1e-6f);
  const int c = tid * 4;
  const float4 gg = *(const float4*)(g + c);
  const float4 bb = *(const float4*)(b + c);
  ushort4 o;
  o.x = bf16bits((x.x - mean) * rstd * gg.x + bb.x);
  o.y = bf16bits((x.y - mean) * rstd * gg.y + bb.y);
  o.z = bf16bits((x.z - mean) * rstd * gg.z + bb.z);
  o.w = bf16bits((x.w - mean) * rstd * gg.w + bb.w);
  *(ushort4*)((unsigned short*)out + (size_t)t * 1024 + c) = o;
}

// ---------------------------------------------------------------------------
// GEMM: C[M,N] = A[M,K] @ Bt[N,K]^T, bf16 inputs, fp32 accum.
// 128x128 tile, BK=64, 256 threads (4 waves, 2x2 of 64x64), 16x16x32 MFMA.
// r4 core (granule-XOR conflict-free LDS; single-buffer; XCD swizzle).
// SWAPPED-OPERAND EPILOGUE: mfma(bfr, af) computes the C^T fragment, so
// D-row (lg*4+j) = N index and D-col (lr) = M index. Each lane's 4 acc
// values span 4 CONSECUTIVE columns -> packed 8B/16B stores (16 per thread
// instead of 64 scalar), wave-stores cover 16 rows x 32 contiguous bytes,
// 4 ni-stores complete full lines for L2 write-combining. MODE 3's row
// permutation is computed once per mi (16x) instead of per element (64x).
// MODE 0: out bf16 = acc + bias
// MODE 1: out bf16 = gelu(acc + bias)
// MODE 2: out f32 += acc + bias     (float4 RMW)
// MODE 3: window-unpartition row perm; out f32[t] = resid[t] + acc + bias
// ---------------------------------------------------------------------------
template<int MODE>
__global__ __launch_bounds__(256)
void gemm_bt_kernel(const __hip_bfloat16* __restrict__ A,
                    const __hip_bfloat16* __restrict__ Bt,
                    const float* __restrict__ bias,
                    void* __restrict__ out,
                    const float* __restrict__ resid,
                    int M, int N, int K) {
  __shared__ __hip_bfloat16 As[128 * 64];
  __shared__ __hip_bfloat16 Bs[128 * 64];
  const int tid = threadIdx.x;
  const int wave = tid >> 6, lane = tid & 63;
  const int lr = lane & 15, lg = lane >> 4;
  // bijective XCD swizzle (m204)
  const unsigned nwg = gridDim.x * gridDim.y;
  const unsigned bid0 = blockIdx.y * gridDim.x + blockIdx.x;
  const unsigned xcd = bid0 & 7u, idx = bid0 >> 3;
  const unsigned q8 = nwg >> 3, r8 = nwg & 7u;
  const unsigned L = (xcd < r8 ? xcd * (q8 + 1u)
                               : r8 * (q8 + 1u) + (xcd - r8) * q8) + idx;
  const int bm = (int)(L / gridDim.x) * 128;
  const int bn = (int)(L % gridDim.x) * 128;
  const int wr = (wave >> 1) * 64, wc = (wave & 1) * 64;
  const int srow = lane >> 3;                       // 0..7 (LDS row mod 8)
  const int scol = ((lane & 7) ^ srow) * 8;         // pre-swizzled source col
  const int rsw = lr & 7;                           // read-side XOR key

  f32x4 acc[4][4] = {};

  for (int k0 = 0; k0 < K; k0 += 64) {
#pragma unroll
    for (int c = 0; c < 4; ++c) {
      const int ch = wave * 4 + c;
      gload16(A + (size_t)(bm + ch * 8 + srow) * K + k0 + scol, &As[ch * 512]);
      gload16(Bt + (size_t)(bn + ch * 8 + srow) * K + k0 + scol, &Bs[ch * 512]);
    }
    __syncthreads();
#pragma unroll
    for (int kk = 0; kk < 64; kk += 32) {
      const int kg = kk >> 3;  // granule base: 0 or 4
      bf16x8 af[4], bfr[4];
#pragma unroll
      for (int i = 0; i < 4; ++i)
        af[i] = *(const bf16x8*)&As[(wr + i * 16 + lr) * 64 + (((kg + lg) ^ rsw) * 8)];
#pragma unroll
      for (int i = 0; i < 4; ++i)
        bfr[i] = *(const bf16x8*)&Bs[(wc + i * 16 + lr) * 64 + (((kg + lg) ^ rsw) * 8)];
#pragma unroll
      for (int mi = 0; mi < 4; ++mi)
#pragma unroll
        for (int ni = 0; ni < 4; ++ni)
          acc[mi][ni] = __builtin_amdgcn_mfma_f32_16x16x32_bf16(bfr[ni], af[mi],
                                                                acc[mi][ni], 0, 0, 0);
    }
    __syncthreads();
  }

  // ---- packed epilogue on the C^T fragment ----
  float4 bv4[4];
#pragma unroll
  for (int ni = 0; ni < 4; ++ni) {
    const int gn0 = bn + wc + ni * 16 + lg * 4;
    if (bias) {
      bv4[ni] = *(const float4*)(bias + gn0);
    } else {
      bv4[ni].x = 0.0f; bv4[ni].y = 0.0f; bv4[ni].z = 0.0f; bv4[ni].w = 0.0f;
    }
  }
#pragma unroll
  for (int mi = 0; mi < 4; ++mi) {
    const int gm = bm + wr + mi * 16 + lr;
    int t2 = gm;
    if (MODE == 3) {
      const int win = gm / 576, s = gm % 576;
      const int bb2 = win / 9, wi = (win % 9) / 3, wj = win % 3;
      t2 = (bb2 * 72 + wi * 24 + (s / 24)) * 72 + wj * 24 + (s % 24);
    }
#pragma unroll
    for (int ni = 0; ni < 4; ++ni) {
      const int gn0 = bn + wc + ni * 16 + lg * 4;
      float v0 = acc[mi][ni][0] + bv4[ni].x;
      float v1 = acc[mi][ni][1] + bv4[ni].y;
      float v2 = acc[mi][ni][2] + bv4[ni].z;
      float v3 = acc[mi][ni][3] + bv4[ni].w;
      if (MODE == 1) {
        v0 = 0.5f * v0 * (1.0f + erff(v0 * 0.70710678f));
        v1 = 0.5f * v1 * (1.0f + erff(v1 * 0.70710678f));
        v2 = 0.5f * v2 * (1.0f + erff(v2 * 0.70710678f));
        v3 = 0.5f * v3 * (1.0f + erff(v3 * 0.70710678f));
      }
      if (MODE == 0 || MODE == 1) {
        ushort4 o;
        o.x = bf16bits(v0); o.y = bf16bits(v1);
        o.z = bf16bits(v2); o.w = bf16bits(v3);
        *(ushort4*)((unsigned short*)out + (size_t)gm * N + gn0) = o;
      } else if (MODE == 2) {
        float4 o = *(float4*)((float*)out + (size_t)gm * N + gn0);
        o.x += v0; o.y += v1; o.z += v2; o.w += v3;
        *(float4*)((float*)out + (size_t)gm * N + gn0) = o;
      } else {
        const float4 rr = *(const float4*)(resid + (size_t)t2 * 1024 + gn0);
        float4 o;
        o.x = rr.x + v0; o.y = rr.y + v1;
        o.z = rr.z + v2; o.w = rr.w + v3;
        *(float4*)((float*)out + (size_t)t2 * 1024 + gn0) = o;
      }
    }
  }
}

// ---------------------------------------------------------------------------
// RoPE + bias + window scatter for Q (pre-scaled by 0.125) and K.
// ---------------------------------------------------------------------------
__global__ __launch_bounds__(256)
void rope_kernel(const __hip_bfloat16* __restrict__ qkvraw,
                 const float* __restrict__ bq, const float* __restrict__ bk,
                 const float* __restrict__ cost, const float* __restrict__ sint,
                 __hip_bfloat16* __restrict__ qw, __hip_bfloat16* __restrict__ kw) {
  const int s = blockIdx.x;    // 0..575
  const int win = blockIdx.y;  // 0..17
  const int b = win / 9, wi = (win % 9) / 3, wj = win % 3;
  const int t = (b * 72 + wi * 24 + (s / 24)) * 72 + wj * 24 + (s % 24);
  const int tid = threadIdx.x;
  const int col = tid * 4;           // 0..1020, aligned pairs
  const int head = col >> 6, d = col & 63;
  const float c0 = cost[s * 64 + d + 0], c1 = cost[s * 64 + d + 1];
  const float c2 = cost[s * 64 + d + 2], c3 = cost[s * 64 + d + 3];
  const float s0 = sint[s * 64 + d + 0], s1 = sint[s * 64 + d + 1];
  const float s2 = sint[s * 64 + d + 2], s3 = sint[s * 64 + d + 3];
  const size_t rbase = (size_t)t * 3072;
  const size_t obase = (((size_t)(win * 16 + head)) * 576 + s) * 64 + d;
  {  // Q (fold softmax scale 1/8)
    const float q0 = __bfloat162float(qkvraw[rbase + col + 0]) + bq[col + 0];
    const float q1 = __bfloat162float(qkvraw[rbase + col + 1]) + bq[col + 1];
    const float q2 = __bfloat162float(qkvraw[rbase + col + 2]) + bq[col + 2];
    const float q3 = __bfloat162float(qkvraw[rbase + col + 3]) + bq[col + 3];
    ushort4 o;
    o.x = bf16bits(0.125f * (q0 * c0 - q1 * s0));
    o.y = bf16bits(0.125f * (q1 * c1 + q0 * s1));
    o.z = bf16bits(0.125f * (q2 * c2 - q3 * s2));
    o.w = bf16bits(0.125f * (q3 * c3 + q2 * s3));
    *(ushort4*)((unsigned short*)qw + obase) = o;
  }
  {  // K
    const float k0 = __bfloat162float(qkvraw[rbase + 1024 + col + 0]) + bk[col + 0];
    const float k1 = __bfloat162float(qkvraw[rbase + 1024 + col + 1]) + bk[col + 1];
    const float k2 = __bfloat162float(qkvraw[rbase + 1024 + col + 2]) + bk[col + 2];
    const float k3 = __bfloat162float(qkvraw[rbase + 1024 + col + 3]) + bk[col + 3];
    ushort4 o;
    o.x = bf16bits(k0 * c0 - k1 * s0);
    o.y = bf16bits(k1 * c1 + k0 * s1);
    o.z = bf16bits(k2 * c2 - k3 * s2);
    o.w = bf16bits(k3 * c3 + k2 * s3);
    *(ushort4*)((unsigned short*)kw + obase) = o;
  }
}

// ---------------------------------------------------------------------------
// V: bias + window gather + transpose: vt[win][head][d][s] bf16 (for PV MFMA)
// ---------------------------------------------------------------------------
__global__ __launch_bounds__(256)
void vtrans_kernel(const __hip_bfloat16* __restrict__ qkvraw,
                   const float* __restrict__ bv,
                   __hip_bfloat16* __restrict__ vt) {
  const int head = blockIdx.x, win = blockIdx.y;
  const int b = win / 9, wi = (win % 9) / 3, wj = win % 3;
  __shared__ __hip_bfloat16 tile[64][72];
  const int tid = threadIdx.x;
  for (int s0 = 0; s0 < 576; s0 += 64) {
#pragma unroll
    for (int rep = 0; rep < 16; ++rep) {
      const int e = rep * 256 + tid;  // 0..4095
      const int si = e >> 6, d = e & 63;
      const int s = s0 + si;
      const int t = (b * 72 + wi * 24 + (s / 24)) * 72 + wj * 24 + (s % 24);
      const float v = __bfloat162float(qkvraw[(size_t)t * 3072 + 2048 + head * 64 + d])
                    + bv[head * 64 + d];
      tile[d][si] = __float2bfloat16(v);
    }
    __syncthreads();
#pragma unroll
    for (int rep = 0; rep < 16; ++rep) {
      const int e = rep * 256 + tid;
      const int d = e >> 6, si = e & 63;
      vt[((size_t)(win * 16 + head) * 64 + d) * 576 + s0 + si] = tile[d][si];
    }
    __syncthreads();
  }
}

// ---------------------------------------------------------------------------
// Flash attention per (qtile, head, win). 256 thr = 4 waves, 16 q-rows/wave.
// K/V LDS uses the granule-XOR swizzle (16-way -> 2-way). (r4 form)
// ---------------------------------------------------------------------------
__global__ __launch_bounds__(256)
void attn_kernel(const __hip_bfloat16* __restrict__ qw,
                 const __hip_bfloat16* __restrict__ kw,
                 const __hip_bfloat16* __restrict__ vt,
                 __hip_bfloat16* __restrict__ ow) {
  __shared__ __hip_bfloat16 Klds[2][64 * 64];
  __shared__ __hip_bfloat16 Vlds[2][64 * 64];
  __shared__ __hip_bfloat16 Plds[4 * 16 * 64];
  const unsigned nwg = gridDim.x * gridDim.y * gridDim.z;
  const unsigned bid0 = (blockIdx.z * gridDim.y + blockIdx.y) * gridDim.x + blockIdx.x;
  const unsigned Lw = (bid0 & 7u) * (nwg >> 3) + (bid0 >> 3);
  const int qt = (int)(Lw % 9u);          // 0..8
  const unsigned r = Lw / 9u;
  const int head = (int)(r & 15u);        // 0..15
  const int win = (int)(r >> 4);          // 0..17
  const int bh = win * 16 + head;
  const int tid = threadIdx.x, wave = tid >> 6, lane = tid & 63;
  const int lr = lane & 15, lg = lane >> 4;
  const int rsw = lr & 7;

  const int qrow = qt * 64 + wave * 16 + lr;
  const __hip_bfloat16* qbase = qw + ((size_t)bh * 576 + qrow) * 64;
  const bf16x8 q0 = *(const bf16x8*)(qbase + lg * 8);
  const bf16x8 q1 = *(const bf16x8*)(qbase + 32 + lg * 8);

  f32x4 oacc[4] = {};
  float mrow[4] = {-1e30f, -1e30f, -1e30f, -1e30f};
  float lrow[4] = {};

  const int srow = lane >> 3;
  const int sw = ((lane & 7) ^ srow) * 8;  // pre-swizzled source col

  auto stagekv = [&](int buf, int kv) {
#pragma unroll
    for (int c = 0; c < 2; ++c) {
      const int ch = wave * 2 + c;
      gload16(kw + ((size_t)bh * 576 + kv * 64 + ch * 8 + srow) * 64 + sw,
              &Klds[buf][ch * 512]);
      gload16(vt + ((size_t)bh * 64 + ch * 8 + srow) * 576 + kv * 64 + sw,
              &Vlds[buf][ch * 512]);
    }
  };

  stagekv(0, 0);
  __syncthreads();

  for (int kv = 0; kv < 9; ++kv) {
    const int cur = kv & 1;
    if (kv + 1 < 9) stagekv(cur ^ 1, kv + 1);
    __builtin_amdgcn_sched_barrier(0);

    f32x4 sfr[4];
#pragma unroll
    for (int c = 0; c < 4; ++c) {
      const bf16x8 b0 = *(const bf16x8*)&Klds[cur][(c * 16 + lr) * 64 + ((lg ^ rsw) * 8)];
      const bf16x8 b1 = *(const bf16x8*)&Klds[cur][(c * 16 + lr) * 64 + (((4 + lg) ^ rsw) * 8)];
      f32x4 z = {};
      z = __builtin_amdgcn_mfma_f32_16x16x32_bf16(q0, b0, z, 0, 0, 0);
      z = __builtin_amdgcn_mfma_f32_16x16x32_bf16(q1, b1, z, 0, 0, 0);
      sfr[c] = z;
    }

    float p[4][4], rscale[4];
#pragma unroll
    for (int j = 0; j < 4; ++j) {
      float mj = fmaxf(fmaxf(sfr[0][j], sfr[1][j]), fmaxf(sfr[2][j], sfr[3][j]));
#pragma unroll
      for (int off = 1; off < 16; off <<= 1) mj = fmaxf(mj, __shfl_xor(mj, off));
      const float mn = fmaxf(mrow[j], mj);
      rscale[j] = __expf(mrow[j] - mn);
      mrow[j] = mn;
      float rs = 0.0f;
#pragma unroll
      for (int c = 0; c < 4; ++c) {
        const float pp = __expf(sfr[c][j] - mn);
        p[c][j] = pp;
        rs += pp;
      }
#pragma unroll
      for (int off = 1; off < 16; off <<= 1) rs += __shfl_xor(rs, off);
      lrow[j] = lrow[j] * rscale[j] + rs;
    }
#pragma unroll
    for (int d = 0; d < 4; ++d)
#pragma unroll
      for (int j = 0; j < 4; ++j) oacc[d][j] *= rscale[j];

#pragma unroll
    for (int c = 0; c < 4; ++c)
#pragma unroll
      for (int j = 0; j < 4; ++j)
        Plds[wave * 1024 + (lg * 4 + j) * 64 + c * 16 + lr] = __float2bfloat16(p[c][j]);

    const bf16x8 pa0 = *(const bf16x8*)&Plds[wave * 1024 + lr * 64 + lg * 8];
    const bf16x8 pa1 = *(const bf16x8*)&Plds[wave * 1024 + lr * 64 + 32 + lg * 8];
#pragma unroll
    for (int d = 0; d < 4; ++d) {
      const bf16x8 v0 = *(const bf16x8*)&Vlds[cur][(d * 16 + lr) * 64 + ((lg ^ rsw) * 8)];
      const bf16x8 v1 = *(const bf16x8*)&Vlds[cur][(d * 16 + lr) * 64 + (((4 + lg) ^ rsw) * 8)];
      oacc[d] = __builtin_amdgcn_mfma_f32_16x16x32_bf16(pa0, v0, oacc[d], 0, 0, 0);
      oacc[d] = __builtin_amdgcn_mfma_f32_16x16x32_bf16(pa1, v1, oacc[d], 0, 0, 0);
    }
    __syncthreads();
  }

#pragma unroll
  for (int j = 0; j < 4; ++j) {
    const float inv = 1.0f / lrow[j];
    const int srow2 = qt * 64 + wave * 16 + lg * 4 + j;
    const size_t base = ((size_t)win * 576 + srow2) * 1024 + head * 64;
#pragma unroll
    for (int d = 0; d < 4; ++d)
      ow[base + d * 16 + lr] = __float2bfloat16(oacc[d][j] * inv);
  }
}

// ---------------------------------------------------------------------------
extern "C" void kernel_launch(void* const* d_in, const int* in_sizes, int n_in,
                              void* d_out, int out_size, void* d_ws, size_t ws_size,
                              hipStream_t stream) {
  const float* hidden = (const float*)d_in[0];
  const float* ln1_g = (const float*)d_in[1];
  const float* ln1_b = (const float*)d_in[2];
  const float* wq = (const float*)d_in[3];
  const float* bq = (const float*)d_in[4];
  const float* wk = (const float*)d_in[5];
  const float* bk = (const float*)d_in[6];
  const float* wv = (const float*)d_in[7];
  const float* bv = (const float*)d_in[8];
  const float* wo = (const float*)d_in[9];
  const float* bo = (const float*)d_in[10];
  const float* ln2_g = (const float*)d_in[11];
  const float* ln2_b = (const float*)d_in[12];
  const float* w1 = (const float*)d_in[13];
  const float* b1 = (const float*)d_in[14];
  const float* w2 = (const float*)d_in[15];
  const float* b2 = (const float*)d_in[16];
  float* out = (float*)d_out;

  char* p = (char*)d_ws;
  auto alloc = [&](size_t bytes) {
    char* r = p;
    p += (bytes + 255) & ~(size_t)255;
    return r;
  };
  __hip_bfloat16* wt_qkv = (__hip_bfloat16*)alloc(3072ull * 1024 * 2);
  __hip_bfloat16* wt_wo  = (__hip_bfloat16*)alloc(1024ull * 1024 * 2);
  __hip_bfloat16* wt_w1  = (__hip_bfloat16*)alloc(4096ull * 1024 * 2);
  __hip_bfloat16* wt_w2  = (__hip_bfloat16*)alloc(1024ull * 4096 * 2);
  float* cost = (float*)alloc(576ull * 64 * 4);
  float* sint = (float*)alloc(576ull * 64 * 4);
  __hip_bfloat16* xbuf = (__hip_bfloat16*)alloc(10368ull * 1024 * 2);  // xln / o_w / xln2
  char* big = alloc(10368ull * 4096 * 2);                              // qkvraw+qw | h1
  __hip_bfloat16* qkvraw = (__hip_bfloat16*)big;
  __hip_bfloat16* qw = (__hip_bfloat16*)(big + 10368ull * 3072 * 2);
  __hip_bfloat16* h1 = (__hip_bfloat16*)big;
  __hip_bfloat16* kw = (__hip_bfloat16*)alloc(18ull * 16 * 576 * 64 * 2);
  __hip_bfloat16* vt = (__hip_bfloat16*)alloc(18ull * 16 * 64 * 576 * 2);

  // weights -> bf16 transposed
  wtrans_kernel<<<dim3(32, 32), 256, 0, stream>>>(wq, wt_qkv, 1024, 1024);
  wtrans_kernel<<<dim3(32, 32), 256, 0, stream>>>(wk, wt_qkv + 1024ull * 1024, 1024, 1024);
  wtrans_kernel<<<dim3(32, 32), 256, 0, stream>>>(wv, wt_qkv + 2048ull * 1024, 1024, 1024);
  wtrans_kernel<<<dim3(32, 32), 256, 0, stream>>>(wo, wt_wo, 1024, 1024);
  wtrans_kernel<<<dim3(128, 32), 256, 0, stream>>>(w1, wt_w1, 1024, 4096);
  wtrans_kernel<<<dim3(32, 128), 256, 0, stream>>>(w2, wt_w2, 4096, 1024);
  tables_kernel<<<576, 64, 0, stream>>>(cost, sint);

  // LN1 -> xln (bf16)
  ln_kernel<<<10368, 256, 0, stream>>>(hidden, ln1_g, ln1_b, xbuf);
  // QKV fused GEMM: [10368,1024] x [3072,1024]^T -> qkvraw bf16
  gemm_bt_kernel<0><<<dim3(24, 81), 256, 0, stream>>>(
      xbuf, wt_qkv, nullptr, qkvraw, nullptr, 10368, 3072, 1024);
  // RoPE + window scatter (q scaled by 0.125); V bias + transpose
  rope_kernel<<<dim3(576, 18), 256, 0, stream>>>(qkvraw, bq, bk, cost, sint, qw, kw);
  vtrans_kernel<<<dim3(16, 18), 256, 0, stream>>>(qkvraw, bv, vt);
  // attention -> o_w (windowed rows, [tw][1024]) into xbuf
  attn_kernel<<<dim3(9, 16, 18), 256, 0, stream>>>(qw, kw, vt, xbuf);
  // Wo GEMM + bias + residual + window-unpartition -> d_out (fp32 x)
  gemm_bt_kernel<3><<<dim3(8, 81), 256, 0, stream>>>(
      xbuf, wt_wo, bo, out, hidden, 10368, 1024, 1024);
  // LN2 -> xln2 (bf16)
  ln_kernel<<<10368, 256, 0, stream>>>(out, ln2_g, ln2_b, xbuf);
  // MLP up + GELU -> h1 bf16
  gemm_bt_kernel<1><<<dim3(32, 81), 256, 0, stream>>>(
      xbuf, wt_w1, b1, h1, nullptr, 10368, 4096, 1024);
  // MLP down, += into d_out
  gemm_bt_kernel<2><<<dim3(8, 81), 256, 0, stream>>>(
      h1, wt_w2, b2, out, nullptr, 10368, 1024, 4096);
}

// Round 7
// 586.771 us; speedup vs baseline: 1.1389x; 1.1030x over previous
//
#include <hip/hip_runtime.h>
#include <hip/hip_bf16.h>

#define DI __device__ __forceinline__

typedef short bf16x8 __attribute__((ext_vector_type(8)));
typedef float f32x4 __attribute__((ext_vector_type(4)));

typedef __attribute__((address_space(3))) unsigned lds_u32;
typedef __attribute__((address_space(1))) const unsigned g_u32;

DI void gload16(const void* g, void* lds) {
  __builtin_amdgcn_global_load_lds((g_u32*)g, (lds_u32*)lds, 16, 0, 0);
}

DI unsigned short bf16bits(float f) {
  __hip_bfloat16 h = __float2bfloat16(f);
  return *(unsigned short*)&h;
}

// ---------------------------------------------------------------------------
// Weight transpose: W[K][N] fp32 -> Wt[N][K] bf16 (tiled via LDS)
// ---------------------------------------------------------------------------
__global__ __launch_bounds__(256)
void wtrans_kernel(const float* __restrict__ w, __hip_bfloat16* __restrict__ wt,
                   int K, int N) {
  __shared__ float tile[32][33];
  const int nb = blockIdx.x * 32, kb = blockIdx.y * 32;
  const int tx = threadIdx.x & 31, ty = threadIdx.x >> 5;  // 32 x 8
#pragma unroll
  for (int i = 0; i < 4; ++i)
    tile[ty + i * 8][tx] = w[(size_t)(kb + ty + i * 8) * N + nb + tx];
  __syncthreads();
#pragma unroll
  for (int i = 0; i < 4; ++i)
    wt[(size_t)(nb + ty + i * 8) * K + kb + tx] = __float2bfloat16(tile[tx][ty + i * 8]);
}

// ---------------------------------------------------------------------------
// RoPE cos/sin tables: [576][64] each
// ---------------------------------------------------------------------------
__global__ void tables_kernel(float* __restrict__ cost, float* __restrict__ sint) {
  const int s = blockIdx.x;    // 0..575
  const int d = threadIdx.x;   // 0..63
  const int j = d >> 1;
  const float pos = (j < 16) ? (float)(s % 24) * (1.0f / 3.0f)
                             : (float)(s / 24) * (1.0f / 3.0f);
  const int fi = j & 15;
  const float freq = powf(10000.0f, -(float)fi * (1.0f / 16.0f));
  const float a = pos * freq;
  cost[s * 64 + d] = cosf(a);
  sint[s * 64 + d] = sinf(a);
}

// ---------------------------------------------------------------------------
// LayerNorm: fp32 in -> bf16 out, one block per token (1024 ch, 256 thr x 4)
// ---------------------------------------------------------------------------
__global__ __launch_bounds__(256)
void ln_kernel(const float* __restrict__ in, const float* __restrict__ g,
               const float* __restrict__ b, __hip_bfloat16* __restrict__ out) {
  const int t = blockIdx.x, tid = threadIdx.x;
  const float4 x = *(const float4*)(in + (size_t)t * 1024 + tid * 4);
  float s = x.x + x.y + x.z + x.w;
  float sq = x.x * x.x + x.y * x.y + x.z * x.z + x.w * x.w;
#pragma unroll
  for (int off = 32; off >= 1; off >>= 1) {
    s += __shfl_down(s, off);
    sq += __shfl_down(sq, off);
  }
  __shared__ float red[8];
  const int wave = tid >> 6, lane = tid & 63;
  if (lane == 0) { red[wave] = s; red[4 + wave] = sq; }
  __syncthreads();
  s = red[0] + red[1] + red[2] + red[3];
  sq = red[4] + red[5] + red[6] + red[7];
  const float mean = s * (1.0f / 1024.0f);
  const float var = sq * (1.0f / 1024.0f) - mean * mean;
  const float rstd = rsqrtf(var + 1e-6f);
  const int c = tid * 4;
  const float4 gg = *(const float4*)(g + c);
  const float4 bb = *(const float4*)(b + c);
  ushort4 o;
  o.x = bf16bits((x.x - mean) * rstd * gg.x + bb.x);
  o.y = bf16bits((x.y - mean) * rstd * gg.y + bb.y);
  o.z = bf16bits((x.z - mean) * rstd * gg.z + bb.z);
  o.w = bf16bits((x.w - mean) * rstd * gg.w + bb.w);
  *(ushort4*)((unsigned short*)out + (size_t)t * 1024 + c) = o;
}

// ---------------------------------------------------------------------------
// GEMM: C[M,N] = A[M,K] @ Bt[N,K]^T, bf16 inputs, fp32 accum.
// 128x128 tile, BK=64, 256 threads (4 waves, 2x2 of 64x64), 16x16x32 MFMA.
// EXACT round-4 core + epilogue (VGPR 84 config; epilogue variants at 88
// VGPR measured 15% slower — do not touch).
// NEW (entry-only): column-grouped rasterization BEFORE the XCD chunking.
// L-space is reordered so each group of 8 consecutive N-tiles is swept
// row-major; an XCD chunk then keeps only 8 B-panels (2MB) live in its L2
// instead of a full grid row (6-8MB > 4MB L2) -> B stays L2-hot, staging
// loads hit L2 (~200cy) instead of HBM (~900cy). gridx%8==0 for all GEMMs;
// for gridx==8 this degenerates to the previous mapping exactly.
// MODE 0: out bf16 = acc + bias
// MODE 1: out bf16 = gelu(acc + bias)
// MODE 2: out f32 += acc + bias
// MODE 3: window-unpartition row perm; out f32[t] = resid[t] + acc + bias
// ---------------------------------------------------------------------------
template<int MODE>
__global__ __launch_bounds__(256)
void gemm_bt_kernel(const __hip_bfloat16* __restrict__ A,
                    const __hip_bfloat16* __restrict__ Bt,
                    const float* __restrict__ bias,
                    void* __restrict__ out,
                    const float* __restrict__ resid,
                    int M, int N, int K) {
  __shared__ __hip_bfloat16 As[128 * 64];
  __shared__ __hip_bfloat16 Bs[128 * 64];
  const int tid = threadIdx.x;
  const int wave = tid >> 6, lane = tid & 63;
  const int lr = lane & 15, lg = lane >> 4;
  // bijective XCD swizzle (m204)
  const unsigned nwg = gridDim.x * gridDim.y;
  const unsigned bid0 = blockIdx.y * gridDim.x + blockIdx.x;
  const unsigned xcd = bid0 & 7u, idx = bid0 >> 3;
  const unsigned q8 = nwg >> 3, r8 = nwg & 7u;
  const unsigned L = (xcd < r8 ? xcd * (q8 + 1u)
                               : r8 * (q8 + 1u) + (xcd - r8) * q8) + idx;
  // column-grouped raster: groups of 8 N-tiles, row-major within a group
  const unsigned gpr = gridDim.y * 8u;          // blocks per column-group
  const unsigned grp = L / gpr, rr = L - grp * gpr;
  const int bm = (int)(rr >> 3) * 128;
  const int bn = (int)(grp * 8u + (rr & 7u)) * 128;
  const int wr = (wave >> 1) * 64, wc = (wave & 1) * 64;
  const int srow = lane >> 3;                       // 0..7 (LDS row mod 8)
  const int scol = ((lane & 7) ^ srow) * 8;         // pre-swizzled source col
  const int rsw = lr & 7;                           // read-side XOR key

  f32x4 acc[4][4] = {};

  for (int k0 = 0; k0 < K; k0 += 64) {
#pragma unroll
    for (int c = 0; c < 4; ++c) {
      const int ch = wave * 4 + c;
      gload16(A + (size_t)(bm + ch * 8 + srow) * K + k0 + scol, &As[ch * 512]);
      gload16(Bt + (size_t)(bn + ch * 8 + srow) * K + k0 + scol, &Bs[ch * 512]);
    }
    __syncthreads();
#pragma unroll
    for (int kk = 0; kk < 64; kk += 32) {
      const int kg = kk >> 3;  // granule base: 0 or 4
      bf16x8 af[4], bfr[4];
#pragma unroll
      for (int i = 0; i < 4; ++i)
        af[i] = *(const bf16x8*)&As[(wr + i * 16 + lr) * 64 + (((kg + lg) ^ rsw) * 8)];
#pragma unroll
      for (int i = 0; i < 4; ++i)
        bfr[i] = *(const bf16x8*)&Bs[(wc + i * 16 + lr) * 64 + (((kg + lg) ^ rsw) * 8)];
#pragma unroll
      for (int mi = 0; mi < 4; ++mi)
#pragma unroll
        for (int ni = 0; ni < 4; ++ni)
          acc[mi][ni] = __builtin_amdgcn_mfma_f32_16x16x32_bf16(af[mi], bfr[ni],
                                                                acc[mi][ni], 0, 0, 0);
    }
    __syncthreads();
  }

#pragma unroll
  for (int ni = 0; ni < 4; ++ni) {
    const int gn = bn + wc + ni * 16 + lr;
    const float bv = bias ? bias[gn] : 0.0f;
#pragma unroll
    for (int mi = 0; mi < 4; ++mi) {
      const int rowb = bm + wr + mi * 16 + lg * 4;
#pragma unroll
      for (int j = 0; j < 4; ++j) {
        const float v = acc[mi][ni][j] + bv;
        const int gm = rowb + j;
        if (MODE == 0) {
          ((__hip_bfloat16*)out)[(size_t)gm * N + gn] = __float2bfloat16(v);
        } else if (MODE == 1) {
          const float gl = 0.5f * v * (1.0f + erff(v * 0.70710678f));
          ((__hip_bfloat16*)out)[(size_t)gm * N + gn] = __float2bfloat16(gl);
        } else if (MODE == 2) {
          ((float*)out)[(size_t)gm * N + gn] += v;
        } else {
          const int win = gm / 576, s = gm % 576;
          const int bb2 = win / 9, wi = (win % 9) / 3, wj = win % 3;
          const int t = (bb2 * 72 + wi * 24 + (s / 24)) * 72 + wj * 24 + (s % 24);
          ((float*)out)[(size_t)t * 1024 + gn] =
              resid[(size_t)t * 1024 + gn] + v;
        }
      }
    }
  }
}

// ---------------------------------------------------------------------------
// RoPE + bias + window scatter for Q (pre-scaled by 0.125) and K.
// ---------------------------------------------------------------------------
__global__ __launch_bounds__(256)
void rope_kernel(const __hip_bfloat16* __restrict__ qkvraw,
                 const float* __restrict__ bq, const float* __restrict__ bk,
                 const float* __restrict__ cost, const float* __restrict__ sint,
                 __hip_bfloat16* __restrict__ qw, __hip_bfloat16* __restrict__ kw) {
  const int s = blockIdx.x;    // 0..575
  const int win = blockIdx.y;  // 0..17
  const int b = win / 9, wi = (win % 9) / 3, wj = win % 3;
  const int t = (b * 72 + wi * 24 + (s / 24)) * 72 + wj * 24 + (s % 24);
  const int tid = threadIdx.x;
  const int col = tid * 4;           // 0..1020, aligned pairs
  const int head = col >> 6, d = col & 63;
  const float c0 = cost[s * 64 + d + 0], c1 = cost[s * 64 + d + 1];
  const float c2 = cost[s * 64 + d + 2], c3 = cost[s * 64 + d + 3];
  const float s0 = sint[s * 64 + d + 0], s1 = sint[s * 64 + d + 1];
  const float s2 = sint[s * 64 + d + 2], s3 = sint[s * 64 + d + 3];
  const size_t rbase = (size_t)t * 3072;
  const size_t obase = (((size_t)(win * 16 + head)) * 576 + s) * 64 + d;
  {  // Q (fold softmax scale 1/8)
    const float q0 = __bfloat162float(qkvraw[rbase + col + 0]) + bq[col + 0];
    const float q1 = __bfloat162float(qkvraw[rbase + col + 1]) + bq[col + 1];
    const float q2 = __bfloat162float(qkvraw[rbase + col + 2]) + bq[col + 2];
    const float q3 = __bfloat162float(qkvraw[rbase + col + 3]) + bq[col + 3];
    ushort4 o;
    o.x = bf16bits(0.125f * (q0 * c0 - q1 * s0));
    o.y = bf16bits(0.125f * (q1 * c1 + q0 * s1));
    o.z = bf16bits(0.125f * (q2 * c2 - q3 * s2));
    o.w = bf16bits(0.125f * (q3 * c3 + q2 * s3));
    *(ushort4*)((unsigned short*)qw + obase) = o;
  }
  {  // K
    const float k0 = __bfloat162float(qkvraw[rbase + 1024 + col + 0]) + bk[col + 0];
    const float k1 = __bfloat162float(qkvraw[rbase + 1024 + col + 1]) + bk[col + 1];
    const float k2 = __bfloat162float(qkvraw[rbase + 1024 + col + 2]) + bk[col + 2];
    const float k3 = __bfloat162float(qkvraw[rbase + 1024 + col + 3]) + bk[col + 3];
    ushort4 o;
    o.x = bf16bits(k0 * c0 - k1 * s0);
    o.y = bf16bits(k1 * c1 + k0 * s1);
    o.z = bf16bits(k2 * c2 - k3 * s2);
    o.w = bf16bits(k3 * c3 + k2 * s3);
    *(ushort4*)((unsigned short*)kw + obase) = o;
  }
}

// ---------------------------------------------------------------------------
// V: bias + window gather + transpose: vt[win][head][d][s] bf16 (for PV MFMA)
// ---------------------------------------------------------------------------
__global__ __launch_bounds__(256)
void vtrans_kernel(const __hip_bfloat16* __restrict__ qkvraw,
                   const float* __restrict__ bv,
                   __hip_bfloat16* __restrict__ vt) {
  const int head = blockIdx.x, win = blockIdx.y;
  const int b = win / 9, wi = (win % 9) / 3, wj = win % 3;
  __shared__ __hip_bfloat16 tile[64][72];
  const int tid = threadIdx.x;
  for (int s0 = 0; s0 < 576; s0 += 64) {
#pragma unroll
    for (int rep = 0; rep < 16; ++rep) {
      const int e = rep * 256 + tid;  // 0..4095
      const int si = e >> 6, d = e & 63;
      const int s = s0 + si;
      const int t = (b * 72 + wi * 24 + (s / 24)) * 72 + wj * 24 + (s % 24);
      const float v = __bfloat162float(qkvraw[(size_t)t * 3072 + 2048 + head * 64 + d])
                    + bv[head * 64 + d];
      tile[d][si] = __float2bfloat16(v);
    }
    __syncthreads();
#pragma unroll
    for (int rep = 0; rep < 16; ++rep) {
      const int e = rep * 256 + tid;
      const int d = e >> 6, si = e & 63;
      vt[((size_t)(win * 16 + head) * 64 + d) * 576 + s0 + si] = tile[d][si];
    }
    __syncthreads();
  }
}

// ---------------------------------------------------------------------------
// Flash attention per (qtile, head, win). 256 thr = 4 waves, 16 q-rows/wave.
// K/V LDS uses the granule-XOR swizzle (16-way -> 2-way). (r4 form, exact)
// ---------------------------------------------------------------------------
__global__ __launch_bounds__(256)
void attn_kernel(const __hip_bfloat16* __restrict__ qw,
                 const __hip_bfloat16* __restrict__ kw,
                 const __hip_bfloat16* __restrict__ vt,
                 __hip_bfloat16* __restrict__ ow) {
  __shared__ __hip_bfloat16 Klds[2][64 * 64];
  __shared__ __hip_bfloat16 Vlds[2][64 * 64];
  __shared__ __hip_bfloat16 Plds[4 * 16 * 64];
  const unsigned nwg = gridDim.x * gridDim.y * gridDim.z;
  const unsigned bid0 = (blockIdx.z * gridDim.y + blockIdx.y) * gridDim.x + blockIdx.x;
  const unsigned Lw = (bid0 & 7u) * (nwg >> 3) + (bid0 >> 3);
  const int qt = (int)(Lw % 9u);          // 0..8
  const unsigned r = Lw / 9u;
  const int head = (int)(r & 15u);        // 0..15
  const int win = (int)(r >> 4);          // 0..17
  const int bh = win * 16 + head;
  const int tid = threadIdx.x, wave = tid >> 6, lane = tid & 63;
  const int lr = lane & 15, lg = lane >> 4;
  const int rsw = lr & 7;

  const int qrow = qt * 64 + wave * 16 + lr;
  const __hip_bfloat16* qbase = qw + ((size_t)bh * 576 + qrow) * 64;
  const bf16x8 q0 = *(const bf16x8*)(qbase + lg * 8);
  const bf16x8 q1 = *(const bf16x8*)(qbase + 32 + lg * 8);

  f32x4 oacc[4] = {};
  float mrow[4] = {-1e30f, -1e30f, -1e30f, -1e30f};
  float lrow[4] = {};

  const int srow = lane >> 3;
  const int sw = ((lane & 7) ^ srow) * 8;  // pre-swizzled source col

  auto stagekv = [&](int buf, int kv) {
#pragma unroll
    for (int c = 0; c < 2; ++c) {
      const int ch = wave * 2 + c;
      gload16(kw + ((size_t)bh * 576 + kv * 64 + ch * 8 + srow) * 64 + sw,
              &Klds[buf][ch * 512]);
      gload16(vt + ((size_t)bh * 64 + ch * 8 + srow) * 576 + kv * 64 + sw,
              &Vlds[buf][ch * 512]);
    }
  };

  stagekv(0, 0);
  __syncthreads();

  for (int kv = 0; kv < 9; ++kv) {
    const int cur = kv & 1;
    if (kv + 1 < 9) stagekv(cur ^ 1, kv + 1);
    __builtin_amdgcn_sched_barrier(0);

    f32x4 sfr[4];
#pragma unroll
    for (int c = 0; c < 4; ++c) {
      const bf16x8 b0 = *(const bf16x8*)&Klds[cur][(c * 16 + lr) * 64 + ((lg ^ rsw) * 8)];
      const bf16x8 b1 = *(const bf16x8*)&Klds[cur][(c * 16 + lr) * 64 + (((4 + lg) ^ rsw) * 8)];
      f32x4 z = {};
      z = __builtin_amdgcn_mfma_f32_16x16x32_bf16(q0, b0, z, 0, 0, 0);
      z = __builtin_amdgcn_mfma_f32_16x16x32_bf16(q1, b1, z, 0, 0, 0);
      sfr[c] = z;
    }

    float p[4][4], rscale[4];
#pragma unroll
    for (int j = 0; j < 4; ++j) {
      float mj = fmaxf(fmaxf(sfr[0][j], sfr[1][j]), fmaxf(sfr[2][j], sfr[3][j]));
#pragma unroll
      for (int off = 1; off < 16; off <<= 1) mj = fmaxf(mj, __shfl_xor(mj, off));
      const float mn = fmaxf(mrow[j], mj);
      rscale[j] = __expf(mrow[j] - mn);
      mrow[j] = mn;
      float rs = 0.0f;
#pragma unroll
      for (int c = 0; c < 4; ++c) {
        const float pp = __expf(sfr[c][j] - mn);
        p[c][j] = pp;
        rs += pp;
      }
#pragma unroll
      for (int off = 1; off < 16; off <<= 1) rs += __shfl_xor(rs, off);
      lrow[j] = lrow[j] * rscale[j] + rs;
    }
#pragma unroll
    for (int d = 0; d < 4; ++d)
#pragma unroll
      for (int j = 0; j < 4; ++j) oacc[d][j] *= rscale[j];

#pragma unroll
    for (int c = 0; c < 4; ++c)
#pragma unroll
      for (int j = 0; j < 4; ++j)
        Plds[wave * 1024 + (lg * 4 + j) * 64 + c * 16 + lr] = __float2bfloat16(p[c][j]);

    const bf16x8 pa0 = *(const bf16x8*)&Plds[wave * 1024 + lr * 64 + lg * 8];
    const bf16x8 pa1 = *(const bf16x8*)&Plds[wave * 1024 + lr * 64 + 32 + lg * 8];
#pragma unroll
    for (int d = 0; d < 4; ++d) {
      const bf16x8 v0 = *(const bf16x8*)&Vlds[cur][(d * 16 + lr) * 64 + ((lg ^ rsw) * 8)];
      const bf16x8 v1 = *(const bf16x8*)&Vlds[cur][(d * 16 + lr) * 64 + (((4 + lg) ^ rsw) * 8)];
      oacc[d] = __builtin_amdgcn_mfma_f32_16x16x32_bf16(pa0, v0, oacc[d], 0, 0, 0);
      oacc[d] = __builtin_amdgcn_mfma_f32_16x16x32_bf16(pa1, v1, oacc[d], 0, 0, 0);
    }
    __syncthreads();
  }

#pragma unroll
  for (int j = 0; j < 4; ++j) {
    const float inv = 1.0f / lrow[j];
    const int srow2 = qt * 64 + wave * 16 + lg * 4 + j;
    const size_t base = ((size_t)win * 576 + srow2) * 1024 + head * 64;
#pragma unroll
    for (int d = 0; d < 4; ++d)
      ow[base + d * 16 + lr] = __float2bfloat16(oacc[d][j] * inv);
  }
}

// ---------------------------------------------------------------------------
extern "C" void kernel_launch(void* const* d_in, const int* in_sizes, int n_in,
                              void* d_out, int out_size, void* d_ws, size_t ws_size,
                              hipStream_t stream) {
  const float* hidden = (const float*)d_in[0];
  const float* ln1_g = (const float*)d_in[1];
  const float* ln1_b = (const float*)d_in[2];
  const float* wq = (const float*)d_in[3];
  const float* bq = (const float*)d_in[4];
  const float* wk = (const float*)d_in[5];
  const float* bk = (const float*)d_in[6];
  const float* wv = (const float*)d_in[7];
  const float* bv = (const float*)d_in[8];
  const float* wo = (const float*)d_in[9];
  const float* bo = (const float*)d_in[10];
  const float* ln2_g = (const float*)d_in[11];
  const float* ln2_b = (const float*)d_in[12];
  const float* w1 = (const float*)d_in[13];
  const float* b1 = (const float*)d_in[14];
  const float* w2 = (const float*)d_in[15];
  const float* b2 = (const float*)d_in[16];
  float* out = (float*)d_out;

  char* p = (char*)d_ws;
  auto alloc = [&](size_t bytes) {
    char* r = p;
    p += (bytes + 255) & ~(size_t)255;
    return r;
  };
  __hip_bfloat16* wt_qkv = (__hip_bfloat16*)alloc(3072ull * 1024 * 2);
  __hip_bfloat16* wt_wo  = (__hip_bfloat16*)alloc(1024ull * 1024 * 2);
  __hip_bfloat16* wt_w1  = (__hip_bfloat16*)alloc(4096ull * 1024 * 2);
  __hip_bfloat16* wt_w2  = (__hip_bfloat16*)alloc(1024ull * 4096 * 2);
  float* cost = (float*)alloc(576ull * 64 * 4);
  float* sint = (float*)alloc(576ull * 64 * 4);
  __hip_bfloat16* xbuf = (__hip_bfloat16*)alloc(10368ull * 1024 * 2);  // xln / o_w / xln2
  char* big = alloc(10368ull * 4096 * 2);                              // qkvraw+qw | h1
  __hip_bfloat16* qkvraw = (__hip_bfloat16*)big;
  __hip_bfloat16* qw = (__hip_bfloat16*)(big + 10368ull * 3072 * 2);
  __hip_bfloat16* h1 = (__hip_bfloat16*)big;
  __hip_bfloat16* kw = (__hip_bfloat16*)alloc(18ull * 16 * 576 * 64 * 2);
  __hip_bfloat16* vt = (__hip_bfloat16*)alloc(18ull * 16 * 64 * 576 * 2);

  // weights -> bf16 transposed
  wtrans_kernel<<<dim3(32, 32), 256, 0, stream>>>(wq, wt_qkv, 1024, 1024);
  wtrans_kernel<<<dim3(32, 32), 256, 0, stream>>>(wk, wt_qkv + 1024ull * 1024, 1024, 1024);
  wtrans_kernel<<<dim3(32, 32), 256, 0, stream>>>(wv, wt_qkv + 2048ull * 1024, 1024, 1024);
  wtrans_kernel<<<dim3(32, 32), 256, 0, stream>>>(wo, wt_wo, 1024, 1024);
  wtrans_kernel<<<dim3(128, 32), 256, 0, stream>>>(w1, wt_w1, 1024, 4096);
  wtrans_kernel<<<dim3(32, 128), 256, 0, stream>>>(w2, wt_w2, 4096, 1024);
  tables_kernel<<<576, 64, 0, stream>>>(cost, sint);

  // LN1 -> xln (bf16)
  ln_kernel<<<10368, 256, 0, stream>>>(hidden, ln1_g, ln1_b, xbuf);
  // QKV fused GEMM: [10368,1024] x [3072,1024]^T -> qkvraw bf16
  gemm_bt_kernel<0><<<dim3(24, 81), 256, 0, stream>>>(
      xbuf, wt_qkv, nullptr, qkvraw, nullptr, 10368, 3072, 1024);
  // RoPE + window scatter (q scaled by 0.125); V bias + transpose
  rope_kernel<<<dim3(576, 18), 256, 0, stream>>>(qkvraw, bq, bk, cost, sint, qw, kw);
  vtrans_kernel<<<dim3(16, 18), 256, 0, stream>>>(qkvraw, bv, vt);
  // attention -> o_w (windowed rows, [tw][1024]) into xbuf
  attn_kernel<<<dim3(9, 16, 18), 256, 0, stream>>>(qw, kw, vt, xbuf);
  // Wo GEMM + bias + residual + window-unpartition -> d_out (fp32 x)
  gemm_bt_kernel<3><<<dim3(8, 81), 256, 0, stream>>>(
      xbuf, wt_wo, bo, out, hidden, 10368, 1024, 1024);
  // LN2 -> xln2 (bf16)
  ln_kernel<<<10368, 256, 0, stream>>>(out, ln2_g, ln2_b, xbuf);
  // MLP up + GELU -> h1 bf16
  gemm_bt_kernel<1><<<dim3(32, 81), 256, 0, stream>>>(
      xbuf, wt_w1, b1, h1, nullptr, 10368, 4096, 1024);
  // MLP down, += into d_out
  gemm_bt_kernel<2><<<dim3(8, 81), 256, 0, stream>>>(
      h1, wt_w2, b2, out, nullptr, 10368, 1024, 4096);
}